// Round 5
// baseline (1401.531 us; speedup 1.0000x reference)
//
#include <hip/hip_runtime.h>

typedef unsigned short u16;
typedef u16  u16x4  __attribute__((ext_vector_type(4)));
typedef u16  u16x8  __attribute__((ext_vector_type(8)));
typedef float f32x4 __attribute__((ext_vector_type(4)));
typedef __bf16 bf16x8 __attribute__((ext_vector_type(8)));

#define D_MODEL 1024
#define DFF     4096
#define SEQ     4096
#define BATCH   4
#define NHEAD   16
#define MROWS   (BATCH*SEQ)   /* 16384 */
#define MCHUNK  4096          /* FFN row-chunk (4 chunks) */

#define BM 128
#define BN 128
#define BK 32

__device__ __forceinline__ float bf2f(u16 u) {
  unsigned v = ((unsigned)u) << 16;
  return __builtin_bit_cast(float, v);
}
__device__ __forceinline__ u16 f2bf(float f) {
  unsigned u = __builtin_bit_cast(unsigned, f);
  u += 0x7fffu + ((u >> 16) & 1u);
  return (u16)(u >> 16);
}

// ---------------- transpose fp32 -> bf16: Wt[n][k] = bf16(W[k][n]) ---------
__global__ __launch_bounds__(256)
void transpose_kernel(const float* __restrict__ W, u16* __restrict__ Wt, int K, int N)
{
  __shared__ u16 tile[32][33];
  const int n0 = blockIdx.x * 32, k0 = blockIdx.y * 32;
  const int tx = threadIdx.x & 31, ty = threadIdx.x >> 5;   // 32 x 8
#pragma unroll
  for (int r = ty; r < 32; r += 8)
    tile[r][tx] = f2bf(W[(size_t)(k0 + r) * N + n0 + tx]);
  __syncthreads();
#pragma unroll
  for (int r = ty; r < 32; r += 8)
    Wt[(size_t)(n0 + r) * K + k0 + tx] = tile[tx][r];
}

// ---------------- LayerNorm: T in (fp32 or bf16) -> bf16 out ---------------
template<typename T>
__global__ __launch_bounds__(256)
void ln_kernel(const T* __restrict__ x, const float* __restrict__ g,
               const float* __restrict__ be, u16* __restrict__ out)
{
  const int row = blockIdx.x;
  const int t = threadIdx.x;
  float v0, v1, v2, v3;
  if constexpr (sizeof(T) == 4) {
    f32x4 u = ((const f32x4*)((const float*)x + (size_t)row * D_MODEL))[t];
    v0 = u.x; v1 = u.y; v2 = u.z; v3 = u.w;
  } else {
    u16x4 u = ((const u16x4*)((const u16*)x + (size_t)row * D_MODEL))[t];
    v0 = bf2f(u.x); v1 = bf2f(u.y); v2 = bf2f(u.z); v3 = bf2f(u.w);
  }
  float s  = v0 + v1 + v2 + v3;
  float s2 = v0*v0 + v1*v1 + v2*v2 + v3*v3;
#pragma unroll
  for (int off = 32; off > 0; off >>= 1) {
    s  += __shfl_down(s,  off);
    s2 += __shfl_down(s2, off);
  }
  __shared__ float red[8];
  if ((t & 63) == 0) { red[t >> 6] = s; red[4 + (t >> 6)] = s2; }
  __syncthreads();
  float S  = red[0] + red[1] + red[2] + red[3];
  float S2 = red[4] + red[5] + red[6] + red[7];
  float mu  = S * (1.f / D_MODEL);
  float var = S2 * (1.f / D_MODEL) - mu * mu;
  var = fmaxf(var, 0.f);
  float rs  = rsqrtf(var + 1e-5f);
  f32x4 gu = ((const f32x4*)g)[t];
  f32x4 bu = ((const f32x4*)be)[t];
  u16x4 o;
  o.x = f2bf((v0 - mu) * rs * gu.x + bu.x);
  o.y = f2bf((v1 - mu) * rs * gu.y + bu.y);
  o.z = f2bf((v2 - mu) * rs * gu.z + bu.z);
  o.w = f2bf((v3 - mu) * rs * gu.w + bu.w);
  ((u16x4*)(out + (size_t)row * D_MODEL))[t] = o;
}

// ---------------- GEMM: C = A(MxK,bf16) @ Bt(NxK,bf16)^T + bias(fp32) ------
// MODE 0: bf16 out = acc+bias
// MODE 1: bf16 out = elu(acc+bias)+1
// MODE 2: bf16 out = acc+bias + res_fp32
// MODE 3: FP32 out = acc+bias + res_bf16   (final output)
template<int MODE>
__global__ __launch_bounds__(256, 2)
void gemm_kernel(const u16* __restrict__ A, const u16* __restrict__ Bt,
                 const float* __restrict__ bias, const void* __restrict__ resv,
                 void* __restrict__ outv, int N, int K)
{
  __shared__ __align__(16) u16 lA[BM * BK];
  __shared__ __align__(16) u16 lB[BN * BK];
  const float* resf = (const float*)resv;
  const u16*   resb = (const u16*)resv;
  const int tid = threadIdx.x;
  const int wave = tid >> 6, lane = tid & 63;
  const int quad = lane >> 4, ln = lane & 15;
  const int bm = blockIdx.y * BM, bn = blockIdx.x * BN;
  const int wm = (wave >> 1) * 64, wn = (wave & 1) * 64;

  f32x4 acc[4][4] = {};

  const int c0 = tid,       r0 = c0 >> 2, q0 = c0 & 3;
  const int c1 = tid + 256, r1 = c1 >> 2, q1 = c1 & 3;
  const u16* gA0 = A  + (size_t)(bm + r0) * K + q0 * 8;
  const u16* gA1 = A  + (size_t)(bm + r1) * K + q1 * 8;
  const u16* gB0 = Bt + (size_t)(bn + r0) * K + q0 * 8;
  const u16* gB1 = Bt + (size_t)(bn + r1) * K + q1 * 8;

  for (int k0 = 0; k0 < K; k0 += BK) {
    u16x8 a0 = *(const u16x8*)(gA0 + k0);
    u16x8 a1 = *(const u16x8*)(gA1 + k0);
    u16x8 b0 = *(const u16x8*)(gB0 + k0);
    u16x8 b1 = *(const u16x8*)(gB1 + k0);
    __syncthreads();                 // previous iter's LDS reads complete
    *(u16x8*)&lA[c0 * 8] = a0;
    *(u16x8*)&lA[c1 * 8] = a1;
    *(u16x8*)&lB[c0 * 8] = b0;
    *(u16x8*)&lB[c1 * 8] = b1;
    __syncthreads();
    bf16x8 af[4], bfr[4];
#pragma unroll
    for (int i = 0; i < 4; ++i) {
      af[i]  = *(const bf16x8*)&lA[(wm + i * 16 + ln) * BK + quad * 8];
      bfr[i] = *(const bf16x8*)&lB[(wn + i * 16 + ln) * BK + quad * 8];
    }
#pragma unroll
    for (int i = 0; i < 4; ++i)
#pragma unroll
      for (int j = 0; j < 4; ++j)
        acc[i][j] = __builtin_amdgcn_mfma_f32_16x16x32_bf16(af[i], bfr[j], acc[i][j], 0, 0, 0);
  }

#pragma unroll
  for (int j = 0; j < 4; ++j) {
    const int col = bn + wn + j * 16 + ln;
    const float bv = bias[col];
#pragma unroll
    for (int i = 0; i < 4; ++i) {
#pragma unroll
      for (int r = 0; r < 4; ++r) {
        const int row = bm + wm + i * 16 + quad * 4 + r;
        const size_t off = (size_t)row * N + col;
        float vv = acc[i][j][r] + bv;
        if (MODE == 1) vv = vv > 0.f ? vv + 1.f : __expf(vv);
        if (MODE == 2) vv += resf[off];
        if (MODE == 3) vv += bf2f(resb[off]);
        if (MODE == 3) ((float*)outv)[off] = vv;      // final output is fp32
        else           ((u16*)outv)[off]   = f2bf(vv);
      }
    }
  }
}

// ---------------- fused FFN1: out = gelu(A@Wg + bg) * (A@Wl + bl) ----------
__global__ __launch_bounds__(256, 2)
void ffn1_kernel(const u16* __restrict__ A, const u16* __restrict__ Wt,
                 const float* __restrict__ b1, u16* __restrict__ out, int K)
{
  __shared__ __align__(16) u16 lA[BM * BK];
  __shared__ __align__(16) u16 lBg[BN * BK];
  __shared__ __align__(16) u16 lBl[BN * BK];
  const int tid = threadIdx.x;
  const int wave = tid >> 6, lane = tid & 63;
  const int quad = lane >> 4, ln = lane & 15;
  const int bm = blockIdx.y * BM, bn = blockIdx.x * BN;
  const int wm = (wave >> 1) * 64, wn = (wave & 1) * 64;

  f32x4 accg[4][4] = {};
  f32x4 accl[4][4] = {};

  const int c0 = tid,       r0 = c0 >> 2, q0 = c0 & 3;
  const int c1 = tid + 256, r1 = c1 >> 2, q1 = c1 & 3;
  const u16* gA0 = A  + (size_t)(bm + r0) * K + q0 * 8;
  const u16* gA1 = A  + (size_t)(bm + r1) * K + q1 * 8;
  const u16* gG0 = Wt + (size_t)(bn + r0) * K + q0 * 8;
  const u16* gG1 = Wt + (size_t)(bn + r1) * K + q1 * 8;
  const u16* gL0 = Wt + (size_t)(DFF + bn + r0) * K + q0 * 8;
  const u16* gL1 = Wt + (size_t)(DFF + bn + r1) * K + q1 * 8;

  for (int k0 = 0; k0 < K; k0 += BK) {
    u16x8 a0 = *(const u16x8*)(gA0 + k0);
    u16x8 a1 = *(const u16x8*)(gA1 + k0);
    u16x8 g0 = *(const u16x8*)(gG0 + k0);
    u16x8 g1 = *(const u16x8*)(gG1 + k0);
    u16x8 l0 = *(const u16x8*)(gL0 + k0);
    u16x8 l1 = *(const u16x8*)(gL1 + k0);
    __syncthreads();
    *(u16x8*)&lA [c0 * 8] = a0;
    *(u16x8*)&lA [c1 * 8] = a1;
    *(u16x8*)&lBg[c0 * 8] = g0;
    *(u16x8*)&lBg[c1 * 8] = g1;
    *(u16x8*)&lBl[c0 * 8] = l0;
    *(u16x8*)&lBl[c1 * 8] = l1;
    __syncthreads();
    bf16x8 af[4], bg[4], bl[4];
#pragma unroll
    for (int i = 0; i < 4; ++i) {
      af[i] = *(const bf16x8*)&lA [(wm + i * 16 + ln) * BK + quad * 8];
      bg[i] = *(const bf16x8*)&lBg[(wn + i * 16 + ln) * BK + quad * 8];
      bl[i] = *(const bf16x8*)&lBl[(wn + i * 16 + ln) * BK + quad * 8];
    }
#pragma unroll
    for (int i = 0; i < 4; ++i)
#pragma unroll
      for (int j = 0; j < 4; ++j) {
        accg[i][j] = __builtin_amdgcn_mfma_f32_16x16x32_bf16(af[i], bg[j], accg[i][j], 0, 0, 0);
        accl[i][j] = __builtin_amdgcn_mfma_f32_16x16x32_bf16(af[i], bl[j], accl[i][j], 0, 0, 0);
      }
  }

#pragma unroll
  for (int j = 0; j < 4; ++j) {
    const int col = bn + wn + j * 16 + ln;
    const float bgv = b1[col];
    const float blv = b1[DFF + col];
#pragma unroll
    for (int i = 0; i < 4; ++i) {
#pragma unroll
      for (int r = 0; r < 4; ++r) {
        const int row = bm + wm + i * 16 + quad * 4 + r;
        float gg = accg[i][j][r] + bgv;
        float ll = accl[i][j][r] + blv;
        float ge = 0.5f * gg * (1.f + erff(gg * 0.70710678118f));
        out[(size_t)row * DFF + col] = f2bf(ge * ll);
      }
    }
  }
}

// ---------------- kv = sum_s k[s,d] * v[s,e]  (per b,h; fp32 atomics) ------
__global__ __launch_bounds__(256)
void zero_kernel(float* __restrict__ p, int n)
{
  int i = blockIdx.x * 256 + threadIdx.x;
  if (i < n) p[i] = 0.f;
}

__global__ __launch_bounds__(256)
void kv_kernel(const u16* __restrict__ kk, const u16* __restrict__ vv,
               float* __restrict__ kv)
{
  const int blk = blockIdx.x;          // (bh)*16 + chunk
  const int chunk = blk & 15;          // 16 chunks of 256 rows
  const int bh = blk >> 4;             // 0..63
  const int t = threadIdx.x;
  const int d = t & 63;
  const int e0 = (t >> 6) * 16;
  float acc[16] = {};
  const size_t base = ((size_t)(bh >> 4) * SEQ + chunk * 256) * D_MODEL + (bh & 15) * 64;
  for (int s = 0; s < 256; ++s) {
    const size_t r = base + (size_t)s * D_MODEL;
    const float kd = bf2f(kk[r + d]);
    const u16x4* vp = (const u16x4*)(vv + r + e0);
#pragma unroll
    for (int i = 0; i < 4; ++i) {
      u16x4 u = vp[i];
      acc[i*4+0] += kd * bf2f(u.x);
      acc[i*4+1] += kd * bf2f(u.y);
      acc[i*4+2] += kd * bf2f(u.z);
      acc[i*4+3] += kd * bf2f(u.w);
    }
  }
  float* outp = kv + ((size_t)bh * 64 + d) * 64 + e0;
#pragma unroll
  for (int i = 0; i < 16; ++i) atomicAdd(outp + i, acc[i]);
}

// ---------------- attn[s,e] = sum_d q[s,d]*kv[d,e] -------------------------
__global__ __launch_bounds__(256)
void attn_kernel(const u16* __restrict__ qq, const float* __restrict__ kv,
                 u16* __restrict__ out)
{
  __shared__ __align__(16) float kvs[64 * 64];
  const int blk = blockIdx.x;          // (bh)*64 + schunk
  const int sc = blk & 63;
  const int bh = blk >> 6;
  const int b = bh >> 4, h = bh & 15;
  const int t = threadIdx.x;
  const f32x4* src = (const f32x4*)(kv + (size_t)bh * 4096);
  for (int i = t; i < 1024; i += 256) ((f32x4*)kvs)[i] = src[i];
  __syncthreads();
  const int sl = t >> 2, e0 = (t & 3) * 16;
  const size_t row = (size_t)b * SEQ + sc * 64 + sl;
  const u16* qp = qq + row * D_MODEL + h * 64;
  float qv[64];
#pragma unroll
  for (int i = 0; i < 16; ++i) {
    u16x4 u = ((const u16x4*)qp)[i];
    qv[i*4+0] = bf2f(u.x); qv[i*4+1] = bf2f(u.y);
    qv[i*4+2] = bf2f(u.z); qv[i*4+3] = bf2f(u.w);
  }
  f32x4 acc[4] = {};
  for (int d = 0; d < 64; ++d) {
    const float qd = qv[d];
    const f32x4* kr = (const f32x4*)(kvs + d * 64 + e0);
#pragma unroll
    for (int i = 0; i < 4; ++i) acc[i] += qd * kr[i];
  }
  u16* op = out + row * D_MODEL + h * 64 + e0;
#pragma unroll
  for (int i = 0; i < 4; ++i) {
    u16x4 o;
    o.x = f2bf(acc[i][0]); o.y = f2bf(acc[i][1]);
    o.z = f2bf(acc[i][2]); o.w = f2bf(acc[i][3]);
    ((u16x4*)op)[i] = o;
  }
}

// ---------------------------------------------------------------------------
// Inputs fp32, OUTPUT FP32. Workspace (peak 128 MB), lifetime-packed:
//   [0,32)MB   : transposed bf16 weights; kvf (1MB fp32) aliases wvt (dead after V)
//   [32,64)MB  : hb (LN1 out, bf16)  -> x1b (attn+res, bf16)
//   [64,96)MB  : kb (K) -> qb (Q) -> hb2 (LN2)
//   [96,128)MB : vb (V) -> attnb -> gbuf (FFN chunk, 32MB)
extern "C" void kernel_launch(void* const* d_in, const int* in_sizes, int n_in,
                              void* d_out, int out_size, void* d_ws, size_t ws_size,
                              hipStream_t stream)
{
  const float* x   = (const float*)d_in[0];
  const float* wq  = (const float*)d_in[1];
  const float* bq  = (const float*)d_in[2];
  const float* wk  = (const float*)d_in[3];
  const float* bk  = (const float*)d_in[4];
  const float* wv  = (const float*)d_in[5];
  const float* bv  = (const float*)d_in[6];
  const float* wo  = (const float*)d_in[7];
  const float* bo  = (const float*)d_in[8];
  const float* w1  = (const float*)d_in[9];
  const float* b1  = (const float*)d_in[10];
  const float* w2  = (const float*)d_in[11];
  const float* b2  = (const float*)d_in[12];
  const float* g1  = (const float*)d_in[13];
  const float* be1 = (const float*)d_in[14];
  const float* g2  = (const float*)d_in[15];
  const float* be2 = (const float*)d_in[16];

  char* ws = (char*)d_ws;
  const size_t MB = 1024ull * 1024ull;
  u16* wqt = (u16*)(ws + 0 * MB);
  u16* wkt = (u16*)(ws + 2 * MB);
  u16* wvt = (u16*)(ws + 4 * MB);
  u16* wot = (u16*)(ws + 6 * MB);
  u16* w1t = (u16*)(ws + 8 * MB);    // 16 MB
  u16* w2t = (u16*)(ws + 24 * MB);   // 8 MB

  u16* hb    = (u16*)(ws + 32 * MB); // LN1 out
  u16* x1b   = (u16*)(ws + 32 * MB); // alias: hb dead after Q gemm
  u16* kb    = (u16*)(ws + 64 * MB);
  u16* qb    = (u16*)(ws + 64 * MB); // alias: kb dead after kv_kernel
  u16* hb2   = (u16*)(ws + 64 * MB); // alias: qb dead after attn
  u16* vb    = (u16*)(ws + 96 * MB);
  u16* attnb = (u16*)(ws + 96 * MB); // alias: vb dead after kv_kernel
  u16* gbuf  = (u16*)(ws + 96 * MB); // alias: attnb dead after O gemm
  float* kvf = (float*)(ws + 4 * MB); // alias wvt: dead after V gemm (1MB used)

  // weight transposes + fp32->bf16 (N x K layout)
  transpose_kernel<<<dim3(32, 32), 256, 0, stream>>>(wq, wqt, 1024, 1024);
  transpose_kernel<<<dim3(32, 32), 256, 0, stream>>>(wk, wkt, 1024, 1024);
  transpose_kernel<<<dim3(32, 32), 256, 0, stream>>>(wv, wvt, 1024, 1024);
  transpose_kernel<<<dim3(32, 32), 256, 0, stream>>>(wo, wot, 1024, 1024);
  transpose_kernel<<<dim3(256, 32), 256, 0, stream>>>(w1, w1t, 1024, 8192);
  transpose_kernel<<<dim3(32, 128), 256, 0, stream>>>(w2, w2t, 4096, 1024);

  // LN1 (fp32 in -> bf16 out)
  ln_kernel<float><<<MROWS, 256, 0, stream>>>(x, g1, be1, hb);

  dim3 gproj(D_MODEL / BN, MROWS / BM);   // (8,128)
  // K, V first (consumed into kv), then Q overwrites kb
  gemm_kernel<1><<<gproj, 256, 0, stream>>>(hb, wkt, bk, nullptr, kb, D_MODEL, D_MODEL);
  gemm_kernel<0><<<gproj, 256, 0, stream>>>(hb, wvt, bv, nullptr, vb, D_MODEL, D_MODEL);

  zero_kernel<<<(64 * 64 * 64 + 255) / 256, 256, 0, stream>>>(kvf, 64 * 64 * 64);
  kv_kernel<<<64 * 16, 256, 0, stream>>>(kb, vb, kvf);

  gemm_kernel<1><<<gproj, 256, 0, stream>>>(hb, wqt, bq, nullptr, qb, D_MODEL, D_MODEL);

  // attn = Q @ kv -> attnb (vb region)
  attn_kernel<<<BATCH * NHEAD * (SEQ / 64), 256, 0, stream>>>(qb, kvf, attnb);

  // out projection + residual(x, fp32) -> x1b (hb region)
  gemm_kernel<2><<<gproj, 256, 0, stream>>>(attnb, wot, bo, x, x1b, D_MODEL, D_MODEL);

  // LN2 (bf16 in -> bf16 out) -> hb2 (qb region)
  ln_kernel<u16><<<MROWS, 256, 0, stream>>>(x1b, g2, be2, hb2);

  // FFN in row-chunks; gbuf (32 MB) reused per chunk; final out is FP32
  for (int c = 0; c < MROWS / MCHUNK; ++c) {
    const size_t ro = (size_t)c * MCHUNK;
    ffn1_kernel<<<dim3(DFF / BN, MCHUNK / BM), 256, 0, stream>>>(
        hb2 + ro * D_MODEL, w1t, b1, gbuf, D_MODEL);
    gemm_kernel<3><<<dim3(D_MODEL / BN, MCHUNK / BM), 256, 0, stream>>>(
        gbuf, w2t, b2, x1b + ro * D_MODEL, (float*)d_out + ro * D_MODEL, D_MODEL, DFF);
  }
}